// Round 3
// baseline (372.879 us; speedup 1.0000x reference)
//
#include <hip/hip_runtime.h>

// Problem constants
#define B_   32
#define CIN  256
#define H_   64
#define W_   64
#define COUT 512
#define G_   9
#define CPG_IN  28          // 252 used input channels / 9 groups
#define HW_  (H_*W_)        // 4096
#define HW4_ (HW_/4)        // 1024 float4 per plane

// Padded s' geometry: padded coord = real + 1; halo (zeros) removes ALL bounds
// checks in kernel C. Row stride 68 floats = 272 B (16B-aligned); plane
// 66*68*4 = 17952 B (16B-aligned). C's f4 loads land on 16B boundaries.
#define HP 66
#define WP 68
#define PLANE (HP*WP)        // 4488 floats
#define VSTRIDE 16           // v padded to [512][16] for aligned scalar loads

typedef float f4 __attribute__((ext_vector_type(4)));

// ---------------------------------------------------------------------------
// Fused prep kernel (was A + B):
//   blocks [0, NMAIN):            s'[b][g][h+1][w+1] = sum_k x[b][28g+k][h][w]
//   blocks [NMAIN, NMAIN+288):    halo-zero one (b,g) plane
//   blocks [NMAIN+288, +128):     v[o][g] reduction of w_pw (4 waves = 4 o's)
// NT flags REMOVED: all BW evidence at 6.3-6.5 TB/s (m13 float4 copy, rocclr
// fills) is with normal L2-routed accesses; nt was the unverified flag on our
// two largest streams. x pollution of L2 is harmless (B completes before C).
// ---------------------------------------------------------------------------
#define NMAIN  (B_*G_*HW4_/256)   // 1152 main blocks
#define NHALO  (B_*G_)            // 288 halo blocks
#define NWRED  (COUT/4)           // 128 w-reduction blocks (4 waves each)

__global__ __launch_bounds__(256) void prep_kernel(const float* __restrict__ x,
                                                   const float* __restrict__ w,
                                                   float* __restrict__ s,
                                                   float* __restrict__ v) {
    const int bid = blockIdx.x;
    const int tid = threadIdx.x;
    if (bid < NMAIN) {
        const int idx = bid * 256 + tid;   // float4 units; total B*9*1024
        const int m  = idx & (HW4_ - 1);
        const int gb = idx >> 10;          // b*9 + g
        const int g  = gb % G_;
        const int b  = gb / G_;
        const int hh = m >> 4;             // row 0..63
        const int ww = (m & 15) * 4;       // col 0..60 step 4
        const f4* xp = (const f4*)x;
        long base = ((long)(b * CIN + g * CPG_IN)) * HW4_ + m;
        f4 acc = (f4)0.0f;
#pragma unroll
        for (int k = 0; k < CPG_IN; ++k) {
            acc += xp[base + (long)k * HW4_];      // normal load (L2-routed)
        }
        float* sp = s + (long)gb * PLANE + (hh + 1) * WP + (ww + 1);
        sp[0] = acc.x; sp[1] = acc.y; sp[2] = acc.z; sp[3] = acc.w;
    } else if (bid < NMAIN + NHALO) {
        // Halo zeroing: rows 0 & 65 full width; cols {0,65,66,67} for rows 1..64.
        const int plane = bid - NMAIN;       // 0..287 = b*9+g
        float* sp = s + (long)plane * PLANE;
#pragma unroll
        for (int pass = 0; pass < 2; ++pass) {
            int i = tid + pass * 256;
            if (i < 392) {
                int p;
                if (i < 68)       p = i;                       // top row
                else if (i < 136) p = 65 * WP + (i - 68);      // bottom row
                else {
                    int k = i - 136;                           // 0..255
                    int r = 1 + (k >> 2);                      // rows 1..64
                    int c = k & 3;                             // 0->col0, 1..3->65..67
                    p = r * WP + (c == 0 ? 0 : 64 + c);
                }
                sp[p] = 0.0f;
            }
        }
    } else {
        // v[o][g] = sum over group g's w_pw columns; one o per wave (4 per block)
        const int o = (bid - NMAIN - NHALO) * 4 + (tid >> 6);
        const int t = tid & 63;
        const float* row = w + o * COUT;
#pragma unroll
        for (int g = 0; g < G_; ++g) {
            float val = (t < 56) ? row[g * 56 + t] : 0.0f;
            if (g == 4 && t >= 56) val = row[504 + (t - 56)];   // miss -> centre
#pragma unroll
            for (int off = 32; off; off >>= 1) val += __shfl_down(val, off);
            if (t == 0) v[o * VSTRIDE + g] = val;
        }
    }
}

// ---------------------------------------------------------------------------
// Kernel C: out[b][o][h][w] = sum_g v[o][g] * s'[b][g][h+g/3][w+g%3] (padded)
// NO LDS, NO barrier, NO bounds checks: per thread, 18 aligned f4 loads from
// the L2/L3-resident padded s' (9 planes x 8 cols covering all three gj
// shifts), then oi-OUTER loop: 4-reg accumulator, one store per output plane.
// Stores are NORMAL (nt removed): fills prove 6.5 TB/s through L2; out-stream
// eviction of s' is absorbed by the 256 MB L3. Store-bound floor ~41 us.
// ---------------------------------------------------------------------------
#define O_TILE 32
#define H_TILE 16

__global__ __launch_bounds__(256, 4) void shift_pw_kernel(const float* __restrict__ s,
                                                          const float* __restrict__ v,
                                                          float* __restrict__ out) {
    const int bid = blockIdx.x;
    const int ot  = bid & 15;         // 16 o-tiles
    const int ht  = (bid >> 4) & 3;   // 4 h-tiles
    const int b   = bid >> 6;         // 32 batches
    const int h0  = ht * H_TILE;
    const int tid = threadIdx.x;
    const int o0  = ot * O_TILE;
    const int w0  = (tid & 15) * 4;   // 16 float4-columns cover W=64
    const int hl  = tid >> 4;         // 16 rows

    // Preload oi-invariant s-values: per g, padded row h0+hl+g/3, cols w0..w0+7.
    // All loads 16B-aligned (row stride 272B, w0*4 multiple of 16).
    const float* sb = s + (long)b * G_ * PLANE;
    f4 sa[G_], sbv[G_];
#pragma unroll
    for (int g = 0; g < G_; ++g) {
        const int gi = g / 3;
        const float* rp = sb + g * PLANE + (h0 + hl + gi) * WP + w0;
        sa[g]  = *(const f4*)rp;
        sbv[g] = *(const f4*)(rp + 4);
    }

    long obase = (((long)b * COUT + o0) * H_ + (h0 + hl)) * W_ + w0;
    const float* vp = v + o0 * VSTRIDE;   // block-uniform -> scalar loads
#pragma unroll
    for (int oi = 0; oi < O_TILE; ++oi) {
        f4 acc = (f4)0.0f;
#pragma unroll
        for (int g = 0; g < G_; ++g) {
            const int gj = g - (g / 3) * 3;
            const float vv = vp[oi * VSTRIDE + g];
            float s0, s1, s2, s3;
            if (gj == 0)      { s0 = sa[g].x; s1 = sa[g].y; s2 = sa[g].z; s3 = sa[g].w; }
            else if (gj == 1) { s0 = sa[g].y; s1 = sa[g].z; s2 = sa[g].w; s3 = sbv[g].x; }
            else              { s0 = sa[g].z; s1 = sa[g].w; s2 = sbv[g].x; s3 = sbv[g].y; }
            acc.x += vv * s0;
            acc.y += vv * s1;
            acc.z += vv * s2;
            acc.w += vv * s3;
        }
        // normal store: each wave's store instruction = 1 KiB contiguous
        *(f4*)(out + obase + (long)oi * HW_) = acc;
    }
}

// ---------------------------------------------------------------------------
extern "C" void kernel_launch(void* const* d_in, const int* in_sizes, int n_in,
                              void* d_out, int out_size, void* d_ws, size_t ws_size,
                              hipStream_t stream) {
    const float* x    = (const float*)d_in[0];   // (32,256,64,64) fp32
    const float* w_pw = (const float*)d_in[1];   // (512,512) fp32
    float* out = (float*)d_out;                  // (32,512,64,64) fp32

    // workspace layout: v[512][16] at 0 (32 KiB exactly), padded s' at 32 KiB
    // (32*9*4488 floats = 5.17 MiB)
    float* v = (float*)d_ws;
    float* s = (float*)((char*)d_ws + 32768);

    // Fused prep: group-sum + halo zero + w reduction in one launch
    prep_kernel<<<NMAIN + NHALO + NWRED, 256, 0, stream>>>(x, w_pw, s, v);

    // Main shifted pointwise, LDS-free, O_TILE=32
    shift_pw_kernel<<<B_ * (H_ / H_TILE) * (COUT / O_TILE), 256, 0, stream>>>(s, v, out);
}

// Round 4
// 361.589 us; speedup vs baseline: 1.0312x; 1.0312x over previous
//
#include <hip/hip_runtime.h>

// Problem constants
#define B_   32
#define CIN  256
#define H_   64
#define W_   64
#define COUT 512
#define G_   9
#define CPG_IN  28          // 252 used input channels / 9 groups
#define HW_  (H_*W_)        // 4096
#define HW4_ (HW_/4)        // 1024 float4 per plane

// Padded s' geometry: padded coord = real + 1; halo (zeros) removes ALL bounds
// checks in kernel C. Row stride 68 floats = 272 B (16B-aligned); plane
// 66*68*4 = 17952 B (16B-aligned). C's f4 loads land on 16B boundaries.
#define HP 66
#define WP 68
#define PLANE (HP*WP)        // 4488 floats
#define VSTRIDE 16           // v padded to [512][16] for aligned scalar loads

typedef float f4 __attribute__((ext_vector_type(4)));

// ---------------------------------------------------------------------------
// Fused prep kernel:
//   blocks [0, NMAIN):        s'[b][g][h+1][w+1] = sum_k x[b][28g+k][h][w]
//                             One block = HALF a (b,g) plane: 512 f4 (2/thread)
//                             -> per k the block reads 8 KB CONTIGUOUS, and the
//                             28-k loop tiles a 448 KB x-slab near-sequentially
//                             (was 4 KB chunks at 16 KB stride = page thrash).
//   blocks [NMAIN, +288):     halo-zero one (b,g) plane
//   blocks [NMAIN+288, +128): v[o][g] reduction of w_pw (4 waves = 4 o's)
// NT RESTORED (round-3 regression): x is touch-once -> NT loads; s' stays
// cached (normal stores).
// ---------------------------------------------------------------------------
#define NMAIN  (B_*G_*2)          // 576 half-plane blocks
#define NHALO  (B_*G_)            // 288 halo blocks
#define NWRED  (COUT/4)           // 128 w-reduction blocks (4 waves each)

__global__ __launch_bounds__(256) void prep_kernel(const float* __restrict__ x,
                                                   const float* __restrict__ w,
                                                   float* __restrict__ s,
                                                   float* __restrict__ v) {
    const int bid = blockIdx.x;
    const int tid = threadIdx.x;
    if (bid < NMAIN) {
        const int gb   = bid >> 1;          // b*9 + g
        const int half = bid & 1;
        const int g  = gb % G_;
        const int b  = gb / G_;
        const int m0 = half * 512 + tid * 2;   // f4 index in plane (0..1022 even)
        const f4* xp = (const f4*)x;
        long base = ((long)(b * CIN + g * CPG_IN)) * HW4_ + m0;
        f4 acc0 = (f4)0.0f, acc1 = (f4)0.0f;
#pragma unroll
        for (int k = 0; k < CPG_IN; ++k) {
            acc0 += __builtin_nontemporal_load(xp + base + (long)k * HW4_);
            acc1 += __builtin_nontemporal_load(xp + base + (long)k * HW4_ + 1);
        }
        const int hh = m0 >> 4;             // row 0..63
        const int ww = (m0 & 15) * 4;       // col 0..56 step 8
        float* sp = s + (long)gb * PLANE + (hh + 1) * WP + (ww + 1);
        sp[0] = acc0.x; sp[1] = acc0.y; sp[2] = acc0.z; sp[3] = acc0.w;
        sp[4] = acc1.x; sp[5] = acc1.y; sp[6] = acc1.z; sp[7] = acc1.w;
    } else if (bid < NMAIN + NHALO) {
        // Halo zeroing: rows 0 & 65 full width; cols {0,65,66,67} for rows 1..64.
        const int plane = bid - NMAIN;       // 0..287 = b*9+g
        float* sp = s + (long)plane * PLANE;
#pragma unroll
        for (int pass = 0; pass < 2; ++pass) {
            int i = tid + pass * 256;
            if (i < 392) {
                int p;
                if (i < 68)       p = i;                       // top row
                else if (i < 136) p = 65 * WP + (i - 68);      // bottom row
                else {
                    int k = i - 136;                           // 0..255
                    int r = 1 + (k >> 2);                      // rows 1..64
                    int c = k & 3;                             // 0->col0, 1..3->65..67
                    p = r * WP + (c == 0 ? 0 : 64 + c);
                }
                sp[p] = 0.0f;
            }
        }
    } else {
        // v[o][g] = sum over group g's w_pw columns; one o per wave (4 per block)
        const int o = (bid - NMAIN - NHALO) * 4 + (tid >> 6);
        const int t = tid & 63;
        const float* row = w + o * COUT;
#pragma unroll
        for (int g = 0; g < G_; ++g) {
            float val = (t < 56) ? row[g * 56 + t] : 0.0f;
            if (g == 4 && t >= 56) val = row[504 + (t - 56)];   // miss -> centre
#pragma unroll
            for (int off = 32; off; off >>= 1) val += __shfl_down(val, off);
            if (t == 0) v[o * VSTRIDE + g] = val;
        }
    }
}

// ---------------------------------------------------------------------------
// Kernel C: out[b][o][h][w] = sum_g v[o][g] * s'[b][g][h+g/3][w+g%3] (padded)
// NO LDS, NO barrier, NO bounds checks: per thread, 18 aligned f4 loads from
// the L2/L3-resident padded s' (9 planes x 8 cols covering all three gj
// shifts), then oi-OUTER loop: 4-reg accumulator, one NT store per output
// plane (NT RESTORED: round-3 showed normal stores cost ~14 us -- touch-once
// output must not occupy L2). O_TILE=32: 18 preloads amortized over 32 planes.
// ---------------------------------------------------------------------------
#define O_TILE 32
#define H_TILE 16

__global__ __launch_bounds__(256, 4) void shift_pw_kernel(const float* __restrict__ s,
                                                          const float* __restrict__ v,
                                                          float* __restrict__ out) {
    const int bid = blockIdx.x;
    const int ot  = bid & 15;         // 16 o-tiles
    const int ht  = (bid >> 4) & 3;   // 4 h-tiles
    const int b   = bid >> 6;         // 32 batches
    const int h0  = ht * H_TILE;
    const int tid = threadIdx.x;
    const int o0  = ot * O_TILE;
    const int w0  = (tid & 15) * 4;   // 16 float4-columns cover W=64
    const int hl  = tid >> 4;         // 16 rows

    // Preload oi-invariant s-values: per g, padded row h0+hl+g/3, cols w0..w0+7.
    // All loads 16B-aligned (row stride 272B, w0*4 multiple of 16).
    const float* sb = s + (long)b * G_ * PLANE;
    f4 sa[G_], sbv[G_];
#pragma unroll
    for (int g = 0; g < G_; ++g) {
        const int gi = g / 3;
        const float* rp = sb + g * PLANE + (h0 + hl + gi) * WP + w0;
        sa[g]  = *(const f4*)rp;
        sbv[g] = *(const f4*)(rp + 4);
    }

    long obase = (((long)b * COUT + o0) * H_ + (h0 + hl)) * W_ + w0;
    const float* vp = v + o0 * VSTRIDE;   // block-uniform -> scalar loads
#pragma unroll
    for (int oi = 0; oi < O_TILE; ++oi) {
        f4 acc = (f4)0.0f;
#pragma unroll
        for (int g = 0; g < G_; ++g) {
            const int gj = g - (g / 3) * 3;
            const float vv = vp[oi * VSTRIDE + g];
            float s0, s1, s2, s3;
            if (gj == 0)      { s0 = sa[g].x; s1 = sa[g].y; s2 = sa[g].z; s3 = sa[g].w; }
            else if (gj == 1) { s0 = sa[g].y; s1 = sa[g].z; s2 = sa[g].w; s3 = sbv[g].x; }
            else              { s0 = sa[g].z; s1 = sa[g].w; s2 = sbv[g].x; s3 = sbv[g].y; }
            acc.x += vv * s0;
            acc.y += vv * s1;
            acc.z += vv * s2;
            acc.w += vv * s3;
        }
        // out is touch-once -> nontemporal; each wave's store = 1 KiB contiguous
        __builtin_nontemporal_store(acc, (f4*)(out + obase + (long)oi * HW_));
    }
}

// ---------------------------------------------------------------------------
extern "C" void kernel_launch(void* const* d_in, const int* in_sizes, int n_in,
                              void* d_out, int out_size, void* d_ws, size_t ws_size,
                              hipStream_t stream) {
    const float* x    = (const float*)d_in[0];   // (32,256,64,64) fp32
    const float* w_pw = (const float*)d_in[1];   // (512,512) fp32
    float* out = (float*)d_out;                  // (32,512,64,64) fp32

    // workspace layout: v[512][16] at 0 (32 KiB exactly), padded s' at 32 KiB
    // (32*9*4488 floats = 5.17 MiB)
    float* v = (float*)d_ws;
    float* s = (float*)((char*)d_ws + 32768);

    // Fused prep: half-plane group-sum + halo zero + w reduction
    prep_kernel<<<NMAIN + NHALO + NWRED, 256, 0, stream>>>(x, w_pw, s, v);

    // Main shifted pointwise, LDS-free, O_TILE=32, NT stores
    shift_pw_kernel<<<B_ * (H_ / H_TILE) * (COUT / O_TILE), 256, 0, stream>>>(s, v, out);
}